// Round 19
// baseline (142.213 us; speedup 1.0000x reference)
//
#include <hip/hip_runtime.h>
#include <hip/hip_bf16.h>
#include <math.h>
#include <stdint.h>

typedef __hip_bfloat16 bf16;
typedef unsigned char u8;
static __device__ __forceinline__ float b2f(bf16 v) { return __bfloat162float(v); }

typedef __bf16 bfx8 __attribute__((ext_vector_type(8)));
typedef float  fx4  __attribute__((ext_vector_type(4)));

constexpr int NN = 200000;   // nodes
constexpr int NE = 600000;   // edges
constexpr int NG = 512;      // graphs
constexpr int KB = 16;       // bucket capacity (Poisson(3): P(deg>16) tiny; overflow path kept)
constexpr int OVFCAP = 8192;

// invalid/padding bucket slots (negative sentinel) map to zero-row NN
static __device__ __forceinline__ int zidx(int s) {
    return ((unsigned)s < (unsigned)NN) ? s : NN;
}

// ---------------- bucket edges by dst + fused misc (counts, W2->bf16T, zero pooled) --------
__global__ void k_bucket(const int* __restrict__ ei, int* __restrict__ cnt,
                         int* __restrict__ bkt, int* __restrict__ ovf, int* __restrict__ novf,
                         const int* __restrict__ batch, float* __restrict__ counts,
                         const float* __restrict__ W2, short* __restrict__ w2t,
                         float* __restrict__ pooled) {
    int t = blockIdx.x * blockDim.x + threadIdx.x;
    if (t < NG * 128) pooled[t] = 0.0f;          // zero pooled (k_l2 atomics target)
    if (t < 64 * 128) {                          // W2 [64][128] fp32 -> w2t [128][64] bf16
        int k = t >> 7, c = t & 127;
        bf16 v = __float2bfloat16(W2[t]);
        w2t[c * 64 + k] = *(const short*)&v;
    }
    if (t < NG) {                                // counts[g] via binary search (batch sorted)
        int g = t;
        int lo = 0, hi = NN;
        while (lo < hi) { int m = (lo + hi) >> 1; if (batch[m] < g) lo = m + 1; else hi = m; }
        int first = lo;
        lo = 0; hi = NN;
        while (lo < hi) { int m = (lo + hi) >> 1; if (batch[m] < g + 1) lo = m + 1; else hi = m; }
        counts[g] = (float)(lo - first);
    }
    if (t >= NE) return;
    int s = ei[t], d = ei[NE + t];
    int slot = atomicAdd(&cnt[d], 1);
    if (slot < KB) bkt[d * KB + slot] = s;
    else { int o = atomicAdd(novf, 1); if (o < OVFCAP) ovf[o] = t; }
}

// ---------------- dis/xs precompute + zero rows + bucket chunk-padding ----------------
__global__ void k_pre(const int* __restrict__ cnt, const float* __restrict__ x,
                      float* __restrict__ dis, float2* __restrict__ xs,
                      u8* __restrict__ h1q, float* __restrict__ scale,
                      int* __restrict__ bkt) {
    int n = blockIdx.x * blockDim.x + threadIdx.x;
    if (n < 16) ((uint*)(h1q + (size_t)NN * 64))[n] = 0;       // h1q zero-row (row NN)
    if (n == 0) scale[NN] = 0.0f;                              // zero-row scale
    if (n == NN) { xs[NN] = make_float2(0.0f, 0.0f); return; } // xs zero-row
    if (n >= NN) return;
    int deg = cnt[n];
    int padEnd = (deg < 4) ? 4 : ((deg + 3) & ~3);
    if (padEnd > KB) padEnd = KB;
    for (int i = deg; i < padEnd; i++) bkt[n * KB + i] = -1;
    float v = rsqrtf((float)deg + 1.0f);
    dis[n] = v;
    float2 xv = ((const float2*)x)[n];
    xs[n] = make_float2(xv.x * v, xv.y * v);
}

// ---------------- fused GCN layer 1: 4 nodes/wave, 16 lanes per node ----------------
// Output: uint8-quantized pre-scaled h1 (q = round(255*v/rowmax), scale = rowmax/255).
// Quant abs error <= 0.2% of rowmax — tighter than bf16's 0.4% relative.
__global__ __launch_bounds__(256) void k_h1g(const int* __restrict__ cnt,
                      const int* __restrict__ bkt, const float* __restrict__ dis,
                      const float2* __restrict__ xs, const float* __restrict__ W1,
                      const float* __restrict__ b1,
                      const int* __restrict__ novf, const int* __restrict__ ovf,
                      const int* __restrict__ ei,
                      u8* __restrict__ h1q, float* __restrict__ scale) {
    int wave = (blockIdx.x * 256 + threadIdx.x) >> 6;   // global wave id
    int lane = threadIdx.x & 63;
    int grp = lane >> 4, l16 = lane & 15;
    int d = wave * 4 + grp;
    if (d >= NN) return;

    int deg = cnt[d];
    int s = bkt[d * KB + l16];
    s = (l16 < deg) ? zidx(s) : NN;          // lanes beyond deg -> zero-row
    float2 ps = xs[s];
    float p0 = ps.x, p1 = ps.y;

    if (deg > KB) {                          // rare overflow
        int nov = *novf; if (nov > OVFCAP) nov = OVFCAP;
        for (int o = l16; o < nov; o += 16) {
            int e = ovf[o];
            if (ei[NE + e] == d) {
                float2 x2 = xs[ei[e]];
                p0 += x2.x; p1 += x2.y;
            }
        }
    }
#pragma unroll
    for (int m = 1; m < 16; m <<= 1) {
        p0 += __shfl_xor(p0, m, 64);
        p1 += __shfl_xor(p1, m, 64);
    }

    float wd = dis[d];
    float2 xd = xs[d];
    float a0 = (p0 + xd.x) * wd;
    float a1 = (p1 + xd.y) * wd;

    int c0 = l16 * 4;
    float4 w0 = *(const float4*)&W1[c0];
    float4 w1 = *(const float4*)&W1[64 + c0];
    float4 bb = *(const float4*)&b1[c0];
    float r0 = fmaxf(a0 * w0.x + a1 * w1.x + bb.x, 0.0f) * wd;
    float r1 = fmaxf(a0 * w0.y + a1 * w1.y + bb.y, 0.0f) * wd;
    float r2 = fmaxf(a0 * w0.z + a1 * w1.z + bb.z, 0.0f) * wd;
    float r3 = fmaxf(a0 * w0.w + a1 * w1.w + bb.w, 0.0f) * wd;

    // per-row uint8 quantization: rowmax via 4-step group max
    float m4 = fmaxf(fmaxf(r0, r1), fmaxf(r2, r3));
#pragma unroll
    for (int m = 1; m < 16; m <<= 1) m4 = fmaxf(m4, __shfl_xor(m4, m, 64));
    float inv = (m4 > 0.0f) ? 255.0f / m4 : 0.0f;
    uint q0 = (uint)__float2int_rn(r0 * inv);
    uint q1 = (uint)__float2int_rn(r1 * inv);
    uint q2 = (uint)__float2int_rn(r2 * inv);
    uint q3 = (uint)__float2int_rn(r3 * inv);
    uint pack = q0 | (q1 << 8) | (q2 << 16) | (q3 << 24);
    ((uint*)h1q)[(size_t)d * 16 + l16] = pack;
    if (l16 == 0) scale[d] = m4 * (1.0f / 255.0f);
}

// ---------------- per-node gather (lane = channel), u8 rows + broadcast scale --------------
static __device__ __forceinline__ float gather16(int d, int lane, int deg, int4 sv,
        const int* __restrict__ bkt, const u8* __restrict__ h1q, const float* __restrict__ scale,
        const int* __restrict__ novf, const int* __restrict__ ovf, const int* __restrict__ ei) {
    float self = scale[d] * (float)h1q[(size_t)d * 64 + lane];   // self term (pre-scaled)
    int s0 = zidx(sv.x), s1 = zidx(sv.y), s2 = zidx(sv.z), s3 = zidx(sv.w);
    float v0 = scale[s0] * (float)h1q[(size_t)s0 * 64 + lane];
    float v1 = scale[s1] * (float)h1q[(size_t)s1 * 64 + lane];
    float v2 = scale[s2] * (float)h1q[(size_t)s2 * 64 + lane];
    float v3 = scale[s3] * (float)h1q[(size_t)s3 * 64 + lane];
    float acc = (self + v0) + ((v1 + v2) + v3);
    if (deg > 4) {
        int4 t = *(const int4*)&bkt[d * KB + 4];
        int b0 = zidx(t.x), b1_ = zidx(t.y), b2_ = zidx(t.z), b3 = zidx(t.w);
        float w0 = scale[b0] * (float)h1q[(size_t)b0 * 64 + lane];
        float w1 = scale[b1_] * (float)h1q[(size_t)b1_ * 64 + lane];
        float w2 = scale[b2_] * (float)h1q[(size_t)b2_ * 64 + lane];
        float w3 = scale[b3] * (float)h1q[(size_t)b3 * 64 + lane];
        acc += (w0 + w1) + (w2 + w3);
        if (deg > 8) {
            int degc = deg < KB ? deg : KB;
            for (int i = 8; i < degc; i += 4) {
                int4 u = *(const int4*)&bkt[d * KB + i];
                int u0 = zidx(u.x), u1 = zidx(u.y), u2 = zidx(u.z), u3 = zidx(u.w);
                float y0 = scale[u0] * (float)h1q[(size_t)u0 * 64 + lane];
                float y1 = scale[u1] * (float)h1q[(size_t)u1 * 64 + lane];
                float y2 = scale[u2] * (float)h1q[(size_t)u2 * 64 + lane];
                float y3 = scale[u3] * (float)h1q[(size_t)u3 * 64 + lane];
                acc += (y0 + y1) + (y2 + y3);
            }
            if (deg > KB) {
                int nov = *novf; if (nov > OVFCAP) nov = OVFCAP;
                for (int o = 0; o < nov; o++) {
                    int e = ovf[o];
                    if (ei[NE + e] == d) {
                        int ss = ei[e];
                        acc += scale[ss] * (float)h1q[(size_t)ss * 64 + lane];
                    }
                }
            }
        }
    }
    return acc;
}

// ---------------- MFMA + pooled epilogue for one 16-node tile (wave does col-tiles wid,wid+4)
static __device__ __forceinline__ void mfma_pool(int n0, int lane, int wid,
        bfx8 af0, bfx8 af1,
        const short* __restrict__ w2t, const float* __restrict__ b2v,
        const int* __restrict__ batch, float* __restrict__ pooled) {
    int lr = lane & 15, lq = lane >> 4;
    int rr0 = n0 + lq * 4;
    int g0 = batch[rr0 + 0], g1 = batch[rr0 + 1];
    int g2 = batch[rr0 + 2], g3 = batch[rr0 + 3];
    bool uni = (batch[n0] == batch[n0 + 15]);

#pragma unroll
    for (int t = 0; t < 2; t++) {
        int c = (wid + t * 4) * 16 + lr;
        const short* bcol = w2t + c * 64 + lq * 8;
        bfx8 bf0 = *(const bfx8*)(bcol);
        bfx8 bf1 = *(const bfx8*)(bcol + 32);
        fx4 acc = {0.0f, 0.0f, 0.0f, 0.0f};
        acc = __builtin_amdgcn_mfma_f32_16x16x32_bf16(af0, bf0, acc, 0, 0, 0);
        acc = __builtin_amdgcn_mfma_f32_16x16x32_bf16(af1, bf1, acc, 0, 0, 0);
        float bias = b2v[c];
        float v0 = fmaxf(acc[0] + bias, 0.0f);
        float v1 = fmaxf(acc[1] + bias, 0.0f);
        float v2 = fmaxf(acc[2] + bias, 0.0f);
        float v3 = fmaxf(acc[3] + bias, 0.0f);
        if (uni) {
            float s = (v0 + v1) + (v2 + v3);
            s += __shfl_xor(s, 16, 64);
            s += __shfl_xor(s, 32, 64);
            if (lq == 0) atomicAdd(&pooled[g0 * 128 + c], s);
        } else {
            float s = v0; int cg = g0;
            if (g1 == cg) s += v1; else { atomicAdd(&pooled[cg * 128 + c], s); s = v1; cg = g1; }
            if (g2 == cg) s += v2; else { atomicAdd(&pooled[cg * 128 + c], s); s = v2; cg = g2; }
            if (g3 == cg) s += v3; else { atomicAdd(&pooled[cg * 128 + c], s); s = v3; cg = g3; }
            atomicAdd(&pooled[cg * 128 + c], s);
        }
    }
}

// ---------------- FUSED layer 2, 2-tile pipeline + early B-heads -----------------------------
__global__ __launch_bounds__(256) void k_l2(const int* __restrict__ cnt,
                        const int* __restrict__ bkt, const float* __restrict__ dis,
                        const u8* __restrict__ h1q, const float* __restrict__ scale,
                        const int* __restrict__ novf, const int* __restrict__ ovf,
                        const int* __restrict__ ei,
                        const short* __restrict__ w2t, const float* __restrict__ b2v,
                        const int* __restrict__ batch, float* __restrict__ pooled) {
    __shared__ short asub[2][16 * 72];       // one buffer per tile, row stride 72
    int tid = threadIdx.x;
    int lane = tid & 63;
    int wid = tid >> 6;                      // 0..3
    int n0A = blockIdx.x * 32;
    int n0B = n0A + 16;
    int dA = n0A + wid * 4;
    int dB = n0B + wid * 4;

    // ---- tile A heads + gather ----
    int4 svA[4]; int degA[4];
#pragma unroll
    for (int i = 0; i < 4; i++) {
        svA[i] = *(const int4*)&bkt[(dA + i) * KB];
        degA[i] = cnt[dA + i];
    }
    float aA[4];
#pragma unroll
    for (int i = 0; i < 4; i++)
        aA[i] = gather16(dA + i, lane, degA[i], svA[i], bkt, h1q, scale, novf, ovf, ei);

    // ---- tile B heads: issue BEFORE the barrier ----
    int4 svB[4]; int degB[4];
#pragma unroll
    for (int i = 0; i < 4; i++) {
        svB[i] = *(const int4*)&bkt[(dB + i) * KB];
        degB[i] = cnt[dB + i];
    }

#pragma unroll
    for (int i = 0; i < 4; i++) {
        bf16 r = __float2bfloat16(aA[i] * dis[dA + i]);
        asub[0][(wid * 4 + i) * 72 + lane] = *(const short*)&r;
    }
    __syncthreads();

    int lr = lane & 15, lq = lane >> 4;
    bfx8 afA0 = *(const bfx8*)&asub[0][lr * 72 + lq * 8];
    bfx8 afA1 = *(const bfx8*)&asub[0][lr * 72 + 32 + lq * 8];

    // ---- gather tile B (overlaps with tile-A MFMA below) ----
    float aB[4];
#pragma unroll
    for (int i = 0; i < 4; i++)
        aB[i] = gather16(dB + i, lane, degB[i], svB[i], bkt, h1q, scale, novf, ovf, ei);

    // ---- MFMA + pool tile A (fills B's load latency) ----
    mfma_pool(n0A, lane, wid, afA0, afA1, w2t, b2v, batch, pooled);

    // ---- write tile B, barrier, MFMA + pool tile B ----
#pragma unroll
    for (int i = 0; i < 4; i++) {
        bf16 r = __float2bfloat16(aB[i] * dis[dB + i]);
        asub[1][(wid * 4 + i) * 72 + lane] = *(const short*)&r;
    }
    __syncthreads();
    bfx8 afB0 = *(const bfx8*)&asub[1][lr * 72 + lq * 8];
    bfx8 afB1 = *(const bfx8*)&asub[1][lr * 72 + 32 + lq * 8];
    mfma_pool(n0B, lane, wid, afB0, afB1, w2t, b2v, batch, pooled);
}

// ---------------- fused head: feat MLP + fusion MLP + sigmoid, block per graph ----------------
__global__ void k_head(const float* __restrict__ feat,
                       const float* __restrict__ fW1, const float* __restrict__ fb1,
                       const float* __restrict__ fg1, const float* __restrict__ fbe1,
                       const float* __restrict__ frm1, const float* __restrict__ frv1,
                       const float* __restrict__ fW2, const float* __restrict__ fb2,
                       const float* __restrict__ uW1, const float* __restrict__ ub1,
                       const float* __restrict__ ug1, const float* __restrict__ ube1,
                       const float* __restrict__ urm1, const float* __restrict__ urv1,
                       const float* __restrict__ uW2, const float* __restrict__ ub2,
                       const float* __restrict__ ug2, const float* __restrict__ ube2,
                       const float* __restrict__ urm2, const float* __restrict__ urv2,
                       const float* __restrict__ uW3, const float* __restrict__ ub3,
                       const float* __restrict__ pooled, const float* __restrict__ counts,
                       float* __restrict__ out) {
    int g = blockIdx.x;
    int tid = threadIdx.x;
    __shared__ float t1[256], c[256], d1[192], d2[128];

    float f[8];
#pragma unroll
    for (int i = 0; i < 8; i++) f[i] = feat[g * 8 + i];

    {
        int j = tid;
        float acc = fb1[j];
#pragma unroll
        for (int i = 0; i < 8; i++) acc += f[i] * fW1[i * 256 + j];
        acc = (acc - frm1[j]) * rsqrtf(frv1[j] + 1e-5f) * fg1[j] + fbe1[j];
        t1[j] = fmaxf(acc, 0.0f);
    }
    __syncthreads();

    if (tid < 128) {
        float acc = fb2[tid];
        for (int j = 0; j < 256; j++) acc += t1[j] * fW2[j * 128 + tid];
        c[128 + tid] = acc;
    } else {
        int k = tid - 128;
        float cnt = fmaxf(counts[g], 1.0f);
        c[k] = pooled[g * 128 + k] / cnt;
    }
    __syncthreads();

    if (tid < 192) {
        float acc = ub1[tid];
        for (int i = 0; i < 256; i++) acc += c[i] * uW1[i * 192 + tid];
        acc = (acc - urm1[tid]) * rsqrtf(urv1[tid] + 1e-5f) * ug1[tid] + ube1[tid];
        d1[tid] = fmaxf(acc, 0.0f);
    }
    __syncthreads();

    if (tid < 128) {
        float acc = ub2[tid];
        for (int i = 0; i < 192; i++) acc += d1[i] * uW2[i * 128 + tid];
        acc = (acc - urm2[tid]) * rsqrtf(urv2[tid] + 1e-5f) * ug2[tid] + ube2[tid];
        d2[tid] = fmaxf(acc, 0.0f);
    }
    __syncthreads();

    if (tid == 0) {
        float s = ub3[0];
        for (int i = 0; i < 128; i++) s += d2[i] * uW3[i];
        out[g] = 1.0f / (1.0f + expf(-s));
    }
}

extern "C" void kernel_launch(void* const* d_in, const int* in_sizes, int n_in,
                              void* d_out, int out_size, void* d_ws, size_t ws_size,
                              hipStream_t stream) {
    const float* x    = (const float*)d_in[0];
    const float* feat = (const float*)d_in[1];
    const float* W1   = (const float*)d_in[2];
    const float* b1   = (const float*)d_in[3];
    const float* W2   = (const float*)d_in[4];
    const float* b2   = (const float*)d_in[5];
    const float* fW1  = (const float*)d_in[6];
    const float* fb1  = (const float*)d_in[7];
    const float* fg1  = (const float*)d_in[8];
    const float* fbe1 = (const float*)d_in[9];
    const float* frm1 = (const float*)d_in[10];
    const float* frv1 = (const float*)d_in[11];
    const float* fW2  = (const float*)d_in[12];
    const float* fb2  = (const float*)d_in[13];
    const float* uW1  = (const float*)d_in[14];
    const float* ub1  = (const float*)d_in[15];
    const float* ug1  = (const float*)d_in[16];
    const float* ube1 = (const float*)d_in[17];
    const float* urm1 = (const float*)d_in[18];
    const float* urv1 = (const float*)d_in[19];
    const float* uW2  = (const float*)d_in[20];
    const float* ub2  = (const float*)d_in[21];
    const float* ug2  = (const float*)d_in[22];
    const float* ube2 = (const float*)d_in[23];
    const float* urm2 = (const float*)d_in[24];
    const float* urv2 = (const float*)d_in[25];
    const float* uW3  = (const float*)d_in[26];
    const float* ub3  = (const float*)d_in[27];
    const int* ei    = (const int*)d_in[28];   // [2, E]
    const int* batch = (const int*)d_in[29];   // [N]
    float* out = (float*)d_out;

    // workspace layout — every buffer 64B-aligned
    auto al = [](char* q) { return (char*)(((uintptr_t)q + 63) & ~(uintptr_t)63); };
    char* p = (char*)d_ws;
    float*  dis    = (float*)p;  p = al(p + (size_t)NN * 4);
    float2* xs     = (float2*)p; p = al(p + (size_t)(NN + 1) * 8);       // x*dis, +zero row
    u8*     h1q    = (u8*)p;     p = al(p + (size_t)(NN + 1) * 64);      // u8 rows, +zero row
    float*  scale  = (float*)p;  p = al(p + (size_t)(NN + 1) * 4);       // per-row scales
    float*  counts = (float*)p;  p = al(p + (size_t)NG * 4);
    float*  pooled = (float*)p;  p = al(p + (size_t)NG * 128 * 4);
    int*    cnt    = (int*)p;    p += (size_t)NN * 4;                    // in-degree / cursor
    int*    novf   = (int*)p;    p = al(p + 4);                          // adjacent to cnt
    int*    ovf    = (int*)p;    p = al(p + (size_t)OVFCAP * 4);
    int*    bkt    = (int*)p;    p = al(p + (size_t)NN * KB * 4);        // bucketed src ids
    short*  w2t    = (short*)p;  p = al(p + (size_t)64 * 128 * 2);       // bf16 W2^T [col][k]

    hipMemsetAsync(cnt, 0, (size_t)NN * 4 + 4, stream);                  // cnt + novf

    // bucket + (counts, W2->bf16T, zero pooled) fused
    k_bucket<<<(NE + 255) / 256, 256, 0, stream>>>(ei, cnt, bkt, ovf, novf,
                                                   batch, counts, W2, w2t, pooled);
    // dis/xs + zero-rows + bucket chunk-padding
    k_pre<<<(NN + 256) / 256, 256, 0, stream>>>(cnt, x, dis, xs, h1q, scale, bkt);

    // GCN layer 1: 4 nodes/wave, 16-lane groups, uint8+scale output
    k_h1g<<<NN / 16, 256, 0, stream>>>(cnt, bkt, dis, xs, W1, b1, novf, ovf, ei, h1q, scale);

    // GCN layer 2: 2-tile pipelined u8 gather+MFMA+pool (block per 32 nodes)
    k_l2<<<NN / 32, 256, 0, stream>>>(cnt, bkt, dis, h1q, scale, novf, ovf, ei,
                                      w2t, b2, batch, pooled);

    // fused MLP head
    k_head<<<NG, 256, 0, stream>>>(feat, fW1, fb1, fg1, fbe1, frm1, frv1, fW2, fb2,
                                   uW1, ub1, ug1, ube1, urm1, urv1,
                                   uW2, ub2, ug2, ube2, urm2, urv2, uW3, ub3,
                                   pooled, counts, out);
}

// Round 20
// 136.060 us; speedup vs baseline: 1.0452x; 1.0452x over previous
//
#include <hip/hip_runtime.h>
#include <hip/hip_bf16.h>
#include <math.h>
#include <stdint.h>

typedef __hip_bfloat16 bf16;
static __device__ __forceinline__ float b2f(bf16 v) { return __bfloat162float(v); }

typedef __bf16 bfx8 __attribute__((ext_vector_type(8)));
typedef float  fx4  __attribute__((ext_vector_type(4)));

constexpr int NN = 200000;   // nodes
constexpr int NE = 600000;   // edges
constexpr int NG = 512;      // graphs
constexpr int KB = 16;       // bucket capacity (Poisson(3): P(deg>16) tiny; overflow path kept)
constexpr int OVFCAP = 8192;

// invalid/padding bucket slots (negative sentinel) map to zero-row NN
static __device__ __forceinline__ int zidx(int s) {
    return ((unsigned)s < (unsigned)NN) ? s : NN;
}

// ---------------- bucket edges by dst + fused misc (counts, W2->bf16T, zero pooled) --------
__global__ void k_bucket(const int* __restrict__ ei, int* __restrict__ cnt,
                         int* __restrict__ bkt, int* __restrict__ ovf, int* __restrict__ novf,
                         const int* __restrict__ batch, float* __restrict__ counts,
                         const float* __restrict__ W2, short* __restrict__ w2t,
                         float* __restrict__ pooled) {
    int t = blockIdx.x * blockDim.x + threadIdx.x;
    if (t < NG * 128) pooled[t] = 0.0f;          // zero pooled (k_l2 atomics target)
    if (t < 64 * 128) {                          // W2 [64][128] fp32 -> w2t [128][64] bf16
        int k = t >> 7, c = t & 127;
        bf16 v = __float2bfloat16(W2[t]);
        w2t[c * 64 + k] = *(const short*)&v;
    }
    if (t < NG) {                                // counts[g] via binary search (batch sorted)
        int g = t;
        int lo = 0, hi = NN;
        while (lo < hi) { int m = (lo + hi) >> 1; if (batch[m] < g) lo = m + 1; else hi = m; }
        int first = lo;
        lo = 0; hi = NN;
        while (lo < hi) { int m = (lo + hi) >> 1; if (batch[m] < g + 1) lo = m + 1; else hi = m; }
        counts[g] = (float)(lo - first);
    }
    if (t >= NE) return;
    int s = ei[t], d = ei[NE + t];
    int slot = atomicAdd(&cnt[d], 1);
    if (slot < KB) bkt[d * KB + slot] = s;
    else { int o = atomicAdd(novf, 1); if (o < OVFCAP) ovf[o] = t; }
}

// ---------------- dis/xs precompute + zero rows + bucket chunk-padding ----------------
// Padding: only slots an int4 chunk will READ need a sentinel: [deg, min(max(4,ceil4(deg)),16)).
// ~1.3 slots/node (~1MB) instead of a 12.8MB 0xFF memset (L2 pollution — round-17 lesson).
__global__ void k_pre(const int* __restrict__ cnt, const float* __restrict__ x,
                      float* __restrict__ dis, float2* __restrict__ xs,
                      bf16* __restrict__ h1s, int* __restrict__ bkt) {
    int n = blockIdx.x * blockDim.x + threadIdx.x;
    if (n < 32) ((uint*)(h1s + (size_t)NN * 64))[n] = 0;   // h1s zero-row (row NN)
    if (n == NN) { xs[NN] = make_float2(0.0f, 0.0f); return; } // xs zero-row
    if (n >= NN) return;
    int deg = cnt[n];
    int padEnd = (deg < 4) ? 4 : ((deg + 3) & ~3);
    if (padEnd > KB) padEnd = KB;
    for (int i = deg; i < padEnd; i++) bkt[n * KB + i] = -1;
    float v = rsqrtf((float)deg + 1.0f);
    dis[n] = v;
    float2 xv = ((const float2*)x)[n];
    xs[n] = make_float2(xv.x * v, xv.y * v);
}

// ---------------- fused GCN layer 1: 4 nodes/wave, 16 lanes per node ----------------
// bf16 PRE-SCALED rows (round-19 lesson: ONE request per edge is the floor — u8+per-row
// scale halved bytes but added a 2nd random request per edge and REGRESSED 48->53us).
__global__ __launch_bounds__(256) void k_h1g(const int* __restrict__ cnt,
                      const int* __restrict__ bkt, const float* __restrict__ dis,
                      const float2* __restrict__ xs, const float* __restrict__ W1,
                      const float* __restrict__ b1,
                      const int* __restrict__ novf, const int* __restrict__ ovf,
                      const int* __restrict__ ei, bf16* __restrict__ h1s) {
    int wave = (blockIdx.x * 256 + threadIdx.x) >> 6;   // global wave id
    int lane = threadIdx.x & 63;
    int grp = lane >> 4, l16 = lane & 15;
    int d = wave * 4 + grp;
    if (d >= NN) return;

    int deg = cnt[d];
    int s = bkt[d * KB + l16];
    s = (l16 < deg) ? zidx(s) : NN;          // lanes beyond deg -> zero-row
    float2 ps = xs[s];
    float p0 = ps.x, p1 = ps.y;

    if (deg > KB) {                          // rare overflow
        int nov = *novf; if (nov > OVFCAP) nov = OVFCAP;
        for (int o = l16; o < nov; o += 16) {
            int e = ovf[o];
            if (ei[NE + e] == d) {
                float2 x2 = xs[ei[e]];
                p0 += x2.x; p1 += x2.y;
            }
        }
    }
#pragma unroll
    for (int m = 1; m < 16; m <<= 1) {
        p0 += __shfl_xor(p0, m, 64);
        p1 += __shfl_xor(p1, m, 64);
    }

    float wd = dis[d];
    float2 xd = xs[d];
    float a0 = (p0 + xd.x) * wd;
    float a1 = (p1 + xd.y) * wd;

    int c0 = l16 * 4;
    float4 w0 = *(const float4*)&W1[c0];
    float4 w1 = *(const float4*)&W1[64 + c0];
    float4 bb = *(const float4*)&b1[c0];
    float r0 = fmaxf(a0 * w0.x + a1 * w1.x + bb.x, 0.0f) * wd;
    float r1 = fmaxf(a0 * w0.y + a1 * w1.y + bb.y, 0.0f) * wd;
    float r2 = fmaxf(a0 * w0.z + a1 * w1.z + bb.z, 0.0f) * wd;
    float r3 = fmaxf(a0 * w0.w + a1 * w1.w + bb.w, 0.0f) * wd;
    bf16 q0 = __float2bfloat16(r0), q1 = __float2bfloat16(r1);
    bf16 q2 = __float2bfloat16(r2), q3 = __float2bfloat16(r3);
    short4 pack = make_short4(*(const short*)&q0, *(const short*)&q1,
                              *(const short*)&q2, *(const short*)&q3);
    *(short4*)&((short*)h1s)[(size_t)d * 64 + c0] = pack;
}

// ---------------- per-node gather (lane = channel), head (bkt int4) preloaded --------------
// Flat 4 unconditional + wave-uniform deg>4 block + deg>8 tail; zero-row kills predication.
static __device__ __forceinline__ float gather16(int d, int lane, int deg, int4 sv,
        const int* __restrict__ bkt, const bf16* __restrict__ h1s,
        const int* __restrict__ novf, const int* __restrict__ ovf, const int* __restrict__ ei) {
    float self = b2f(h1s[(size_t)d * 64 + lane]);        // self term (pre-scaled)
    int s0 = zidx(sv.x), s1 = zidx(sv.y), s2 = zidx(sv.z), s3 = zidx(sv.w);
    float v0 = b2f(h1s[(size_t)s0 * 64 + lane]);
    float v1 = b2f(h1s[(size_t)s1 * 64 + lane]);
    float v2 = b2f(h1s[(size_t)s2 * 64 + lane]);
    float v3 = b2f(h1s[(size_t)s3 * 64 + lane]);
    float acc = (self + v0) + ((v1 + v2) + v3);          // tree-ish
    if (deg > 4) {
        int4 t = *(const int4*)&bkt[d * KB + 4];
        int b0 = zidx(t.x), b1_ = zidx(t.y), b2_ = zidx(t.z), b3 = zidx(t.w);
        float w0 = b2f(h1s[(size_t)b0 * 64 + lane]);
        float w1 = b2f(h1s[(size_t)b1_ * 64 + lane]);
        float w2 = b2f(h1s[(size_t)b2_ * 64 + lane]);
        float w3 = b2f(h1s[(size_t)b3 * 64 + lane]);
        acc += (w0 + w1) + (w2 + w3);
        if (deg > 8) {
            int degc = deg < KB ? deg : KB;
            for (int i = 8; i < degc; i += 4) {
                int4 u = *(const int4*)&bkt[d * KB + i];
                float y0 = b2f(h1s[(size_t)zidx(u.x) * 64 + lane]);
                float y1 = b2f(h1s[(size_t)zidx(u.y) * 64 + lane]);
                float y2 = b2f(h1s[(size_t)zidx(u.z) * 64 + lane]);
                float y3 = b2f(h1s[(size_t)zidx(u.w) * 64 + lane]);
                acc += (y0 + y1) + (y2 + y3);
            }
            if (deg > KB) {
                int nov = *novf; if (nov > OVFCAP) nov = OVFCAP;
                for (int o = 0; o < nov; o++) {
                    int e = ovf[o];
                    if (ei[NE + e] == d) acc += b2f(h1s[(size_t)ei[e] * 64 + lane]);
                }
            }
        }
    }
    return acc;
}

// ---------------- MFMA + pooled epilogue for one 16-node tile (wave does col-tiles wid,wid+4)
static __device__ __forceinline__ void mfma_pool(int n0, int lane, int wid,
        bfx8 af0, bfx8 af1,
        const short* __restrict__ w2t, const float* __restrict__ b2v,
        const int* __restrict__ batch, float* __restrict__ pooled) {
    int lr = lane & 15, lq = lane >> 4;
    int rr0 = n0 + lq * 4;
    int g0 = batch[rr0 + 0], g1 = batch[rr0 + 1];
    int g2 = batch[rr0 + 2], g3 = batch[rr0 + 3];
    bool uni = (batch[n0] == batch[n0 + 15]);

#pragma unroll
    for (int t = 0; t < 2; t++) {
        int c = (wid + t * 4) * 16 + lr;
        const short* bcol = w2t + c * 64 + lq * 8;
        bfx8 bf0 = *(const bfx8*)(bcol);
        bfx8 bf1 = *(const bfx8*)(bcol + 32);
        fx4 acc = {0.0f, 0.0f, 0.0f, 0.0f};
        acc = __builtin_amdgcn_mfma_f32_16x16x32_bf16(af0, bf0, acc, 0, 0, 0);
        acc = __builtin_amdgcn_mfma_f32_16x16x32_bf16(af1, bf1, acc, 0, 0, 0);
        float bias = b2v[c];
        float v0 = fmaxf(acc[0] + bias, 0.0f);
        float v1 = fmaxf(acc[1] + bias, 0.0f);
        float v2 = fmaxf(acc[2] + bias, 0.0f);
        float v3 = fmaxf(acc[3] + bias, 0.0f);
        if (uni) {
            float s = (v0 + v1) + (v2 + v3);
            s += __shfl_xor(s, 16, 64);
            s += __shfl_xor(s, 32, 64);
            if (lq == 0) atomicAdd(&pooled[g0 * 128 + c], s);
        } else {
            float s = v0; int cg = g0;
            if (g1 == cg) s += v1; else { atomicAdd(&pooled[cg * 128 + c], s); s = v1; cg = g1; }
            if (g2 == cg) s += v2; else { atomicAdd(&pooled[cg * 128 + c], s); s = v2; cg = g2; }
            if (g3 == cg) s += v3; else { atomicAdd(&pooled[cg * 128 + c], s); s = v3; cg = g3; }
            atomicAdd(&pooled[cg * 128 + c], s);
        }
    }
}

// ---------------- FUSED layer 2, 2-tile pipeline + early B-heads -----------------------------
__global__ __launch_bounds__(256) void k_l2(const int* __restrict__ cnt,
                        const int* __restrict__ bkt, const float* __restrict__ dis,
                        const bf16* __restrict__ h1s,
                        const int* __restrict__ novf, const int* __restrict__ ovf,
                        const int* __restrict__ ei,
                        const short* __restrict__ w2t, const float* __restrict__ b2v,
                        const int* __restrict__ batch, float* __restrict__ pooled) {
    __shared__ short asub[2][16 * 72];       // one buffer per tile, row stride 72
    int tid = threadIdx.x;
    int lane = tid & 63;
    int wid = tid >> 6;                      // 0..3
    int n0A = blockIdx.x * 32;
    int n0B = n0A + 16;
    int dA = n0A + wid * 4;
    int dB = n0B + wid * 4;

    // ---- tile A heads + gather ----
    int4 svA[4]; int degA[4];
#pragma unroll
    for (int i = 0; i < 4; i++) {
        svA[i] = *(const int4*)&bkt[(dA + i) * KB];
        degA[i] = cnt[dA + i];
    }
    float aA[4];
#pragma unroll
    for (int i = 0; i < 4; i++)
        aA[i] = gather16(dA + i, lane, degA[i], svA[i], bkt, h1s, novf, ovf, ei);

    // ---- tile B heads: issue BEFORE the barrier ----
    int4 svB[4]; int degB[4];
#pragma unroll
    for (int i = 0; i < 4; i++) {
        svB[i] = *(const int4*)&bkt[(dB + i) * KB];
        degB[i] = cnt[dB + i];
    }

#pragma unroll
    for (int i = 0; i < 4; i++) {
        bf16 r = __float2bfloat16(aA[i] * dis[dA + i]);
        asub[0][(wid * 4 + i) * 72 + lane] = *(const short*)&r;
    }
    __syncthreads();

    int lr = lane & 15, lq = lane >> 4;
    bfx8 afA0 = *(const bfx8*)&asub[0][lr * 72 + lq * 8];
    bfx8 afA1 = *(const bfx8*)&asub[0][lr * 72 + 32 + lq * 8];

    // ---- gather tile B (overlaps with tile-A MFMA below) ----
    float aB[4];
#pragma unroll
    for (int i = 0; i < 4; i++)
        aB[i] = gather16(dB + i, lane, degB[i], svB[i], bkt, h1s, novf, ovf, ei);

    // ---- MFMA + pool tile A (fills B's load latency) ----
    mfma_pool(n0A, lane, wid, afA0, afA1, w2t, b2v, batch, pooled);

    // ---- write tile B, barrier, MFMA + pool tile B ----
#pragma unroll
    for (int i = 0; i < 4; i++) {
        bf16 r = __float2bfloat16(aB[i] * dis[dB + i]);
        asub[1][(wid * 4 + i) * 72 + lane] = *(const short*)&r;
    }
    __syncthreads();
    bfx8 afB0 = *(const bfx8*)&asub[1][lr * 72 + lq * 8];
    bfx8 afB1 = *(const bfx8*)&asub[1][lr * 72 + 32 + lq * 8];
    mfma_pool(n0B, lane, wid, afB0, afB1, w2t, b2v, batch, pooled);
}

// ---------------- fused head: feat MLP + fusion MLP + sigmoid, block per graph ----------------
__global__ void k_head(const float* __restrict__ feat,
                       const float* __restrict__ fW1, const float* __restrict__ fb1,
                       const float* __restrict__ fg1, const float* __restrict__ fbe1,
                       const float* __restrict__ frm1, const float* __restrict__ frv1,
                       const float* __restrict__ fW2, const float* __restrict__ fb2,
                       const float* __restrict__ uW1, const float* __restrict__ ub1,
                       const float* __restrict__ ug1, const float* __restrict__ ube1,
                       const float* __restrict__ urm1, const float* __restrict__ urv1,
                       const float* __restrict__ uW2, const float* __restrict__ ub2,
                       const float* __restrict__ ug2, const float* __restrict__ ube2,
                       const float* __restrict__ urm2, const float* __restrict__ urv2,
                       const float* __restrict__ uW3, const float* __restrict__ ub3,
                       const float* __restrict__ pooled, const float* __restrict__ counts,
                       float* __restrict__ out) {
    int g = blockIdx.x;
    int tid = threadIdx.x;
    __shared__ float t1[256], c[256], d1[192], d2[128];

    float f[8];
#pragma unroll
    for (int i = 0; i < 8; i++) f[i] = feat[g * 8 + i];

    {
        int j = tid;
        float acc = fb1[j];
#pragma unroll
        for (int i = 0; i < 8; i++) acc += f[i] * fW1[i * 256 + j];
        acc = (acc - frm1[j]) * rsqrtf(frv1[j] + 1e-5f) * fg1[j] + fbe1[j];
        t1[j] = fmaxf(acc, 0.0f);
    }
    __syncthreads();

    if (tid < 128) {
        float acc = fb2[tid];
        for (int j = 0; j < 256; j++) acc += t1[j] * fW2[j * 128 + tid];
        c[128 + tid] = acc;
    } else {
        int k = tid - 128;
        float cnt = fmaxf(counts[g], 1.0f);
        c[k] = pooled[g * 128 + k] / cnt;
    }
    __syncthreads();

    if (tid < 192) {
        float acc = ub1[tid];
        for (int i = 0; i < 256; i++) acc += c[i] * uW1[i * 192 + tid];
        acc = (acc - urm1[tid]) * rsqrtf(urv1[tid] + 1e-5f) * ug1[tid] + ube1[tid];
        d1[tid] = fmaxf(acc, 0.0f);
    }
    __syncthreads();

    if (tid < 128) {
        float acc = ub2[tid];
        for (int i = 0; i < 192; i++) acc += d1[i] * uW2[i * 128 + tid];
        acc = (acc - urm2[tid]) * rsqrtf(urv2[tid] + 1e-5f) * ug2[tid] + ube2[tid];
        d2[tid] = fmaxf(acc, 0.0f);
    }
    __syncthreads();

    if (tid == 0) {
        float s = ub3[0];
        for (int i = 0; i < 128; i++) s += d2[i] * uW3[i];
        out[g] = 1.0f / (1.0f + expf(-s));
    }
}

extern "C" void kernel_launch(void* const* d_in, const int* in_sizes, int n_in,
                              void* d_out, int out_size, void* d_ws, size_t ws_size,
                              hipStream_t stream) {
    const float* x    = (const float*)d_in[0];
    const float* feat = (const float*)d_in[1];
    const float* W1   = (const float*)d_in[2];
    const float* b1   = (const float*)d_in[3];
    const float* W2   = (const float*)d_in[4];
    const float* b2   = (const float*)d_in[5];
    const float* fW1  = (const float*)d_in[6];
    const float* fb1  = (const float*)d_in[7];
    const float* fg1  = (const float*)d_in[8];
    const float* fbe1 = (const float*)d_in[9];
    const float* frm1 = (const float*)d_in[10];
    const float* frv1 = (const float*)d_in[11];
    const float* fW2  = (const float*)d_in[12];
    const float* fb2  = (const float*)d_in[13];
    const float* uW1  = (const float*)d_in[14];
    const float* ub1  = (const float*)d_in[15];
    const float* ug1  = (const float*)d_in[16];
    const float* ube1 = (const float*)d_in[17];
    const float* urm1 = (const float*)d_in[18];
    const float* urv1 = (const float*)d_in[19];
    const float* uW2  = (const float*)d_in[20];
    const float* ub2  = (const float*)d_in[21];
    const float* ug2  = (const float*)d_in[22];
    const float* ube2 = (const float*)d_in[23];
    const float* urm2 = (const float*)d_in[24];
    const float* urv2 = (const float*)d_in[25];
    const float* uW3  = (const float*)d_in[26];
    const float* ub3  = (const float*)d_in[27];
    const int* ei    = (const int*)d_in[28];   // [2, E]
    const int* batch = (const int*)d_in[29];   // [N]
    float* out = (float*)d_out;

    // workspace layout — every buffer 64B-aligned
    auto al = [](char* q) { return (char*)(((uintptr_t)q + 63) & ~(uintptr_t)63); };
    char* p = (char*)d_ws;
    float*  dis    = (float*)p;  p = al(p + (size_t)NN * 4);
    float2* xs     = (float2*)p; p = al(p + (size_t)(NN + 1) * 8);       // x*dis, +zero row
    bf16*   h1s    = (bf16*)p;   p = al(p + (size_t)(NN + 1) * 64 * 2);  // relu(h1)*dis, +zero row
    float*  counts = (float*)p;  p = al(p + (size_t)NG * 4);
    float*  pooled = (float*)p;  p = al(p + (size_t)NG * 128 * 4);
    int*    cnt    = (int*)p;    p += (size_t)NN * 4;                    // in-degree / cursor
    int*    novf   = (int*)p;    p = al(p + 4);                          // adjacent to cnt
    int*    ovf    = (int*)p;    p = al(p + (size_t)OVFCAP * 4);
    int*    bkt    = (int*)p;    p = al(p + (size_t)NN * KB * 4);        // bucketed src ids
    short*  w2t    = (short*)p;  p = al(p + (size_t)64 * 128 * 2);       // bf16 W2^T [col][k]

    hipMemsetAsync(cnt, 0, (size_t)NN * 4 + 4, stream);                  // cnt + novf

    // bucket + (counts, W2->bf16T, zero pooled) fused
    k_bucket<<<(NE + 255) / 256, 256, 0, stream>>>(ei, cnt, bkt, ovf, novf,
                                                   batch, counts, W2, w2t, pooled);
    // dis/xs + zero-rows + bucket chunk-padding (~1MB writes)
    k_pre<<<(NN + 256) / 256, 256, 0, stream>>>(cnt, x, dis, xs, h1s, bkt);

    // GCN layer 1: 4 nodes/wave, 16-lane groups
    k_h1g<<<NN / 16, 256, 0, stream>>>(cnt, bkt, dis, xs, W1, b1, novf, ovf, ei, h1s);

    // GCN layer 2: 2-tile pipelined gather+MFMA+pool, early B-heads (block per 32 nodes)
    k_l2<<<NN / 32, 256, 0, stream>>>(cnt, bkt, dis, h1s, novf, ovf, ei,
                                      w2t, b2, batch, pooled);

    // fused MLP head
    k_head<<<NG, 256, 0, stream>>>(feat, fW1, fb1, fg1, fbe1, frm1, frv1, fW2, fb2,
                                   uW1, ub1, ug1, ube1, urm1, urv1,
                                   uW2, ub2, ug2, ube2, urm2, urv2, uW3, ub3,
                                   pooled, counts, out);
}